// Round 10
// baseline (212.542 us; speedup 1.0000x reference)
//
#include <hip/hip_runtime.h>

// entmax-1.5 attention: B=8,H=8,S=1024,D=64, fp32 in/out.
// Prepass (fused): K -> bf16 ws; V -> bf16 transposed [bh][d][s] ws.
// Main (round-10): 16 q-rows/block. K/V fragments loaded DIRECTLY from
// global into registers with EXPLICIT 2-tile-ahead software pipelining
// (fragment regs rotated; loads for tile kt+2 issued at iter kt; compiler
// inserts counted vmcnt before consumption). L2-residency proven in r7
// (FETCH flat): XCD swizzle pins each bh's 64 blocks to one XCD, 8bh x
// 256KB = 2MB K/V per private 4MB L2. r7's regression was unpipelined
// in-iteration loads + setprio fencing the scheduler — both fixed here.
// sT deleted: LDS 52K->35.8K => 4 blocks/CU (16 waves). No inline-asm
// waits; 3 __syncthreads only. setprio removed from GEMM loops.
// bf16 packing: manual f2bf RNE + v_perm_b32 pair-pack (same rounding bits).
// v_cvt_pk_bf16_f32 inline asm NaN'd in rounds 1-3 bisection — BANNED.
// entmax: per-row Newton (5 iters, renorm absorbs residual), reg-pinned
// scores, packed-f32 math, DPP row_ror reduces, 4-way accumulator trees.
// GEMM2 dual MFMA accumulator + 1-ahead sP A-fragment prefetch.

#define S_LEN 1024
#define D_DIM 64
#define TQ    16
#define TK    64
#define NT    (S_LEN / TK)    // 16 tiles
#define QPAD  72              // sQ row stride (bf16 elems)
#define PPAD  1032            // sP row stride (bf16 elems; 1032 => row stride
                              // == 4 banks mod 32: load-bearing for GEMM2-A reads)

typedef short  short8   __attribute__((ext_vector_type(8)));
typedef float  f32x4    __attribute__((ext_vector_type(4)));
typedef float  f32x2    __attribute__((ext_vector_type(2)));

static __device__ __forceinline__ unsigned short f2bf(float f) {
    unsigned u = __builtin_bit_cast(unsigned, f);
    u += 0x7FFFu + ((u >> 16) & 1u);           // RNE
    return (unsigned short)(u >> 16);
}
// RNE-round two f32 and pack their bf16s into one u32 via v_perm_b32.
// Bit-identical to f2bf(lo) | (f2bf(hi)<<16), fewer instructions.
static __device__ __forceinline__ unsigned bfpack(float lo, float hi) {
    unsigned ulo = __builtin_bit_cast(unsigned, lo);
    unsigned uhi = __builtin_bit_cast(unsigned, hi);
    ulo += 0x7FFFu + ((ulo >> 16) & 1u);
    uhi += 0x7FFFu + ((uhi >> 16) & 1u);
    return __builtin_amdgcn_perm(uhi, ulo, 0x07060302u);  // {uhi[31:16], ulo[31:16]}
}
static __device__ __forceinline__ float bf_lo(unsigned u) {
    return __builtin_bit_cast(float, u << 16);
}
static __device__ __forceinline__ float bf_hi(unsigned u) {
    return __builtin_bit_cast(float, u & 0xFFFF0000u);
}

// 16-lane reduces via DPP row_ror (row = 16 lanes on CDNA). Rotation set
// {8,4,2,1} reaches all 16 lanes; VALU-speed vs ds_swizzle's ~30cyc.
template<int C>
static __device__ __forceinline__ float dppmov(float v) {
    return __builtin_bit_cast(float,
        __builtin_amdgcn_update_dpp(0, __builtin_bit_cast(int, v), C, 0xF, 0xF, true));
}
static __device__ __forceinline__ float red16_sum(float v) {
    v += dppmov<0x128>(v);   // row_ror:8
    v += dppmov<0x124>(v);   // row_ror:4
    v += dppmov<0x122>(v);   // row_ror:2
    v += dppmov<0x121>(v);   // row_ror:1
    return v;
}
static __device__ __forceinline__ float red16_max(float v) {
    v = fmaxf(v, dppmov<0x128>(v));
    v = fmaxf(v, dppmov<0x124>(v));
    v = fmaxf(v, dppmov<0x122>(v));
    v = fmaxf(v, dppmov<0x121>(v));
    return v;
}
// packed 2-channel 16-lane sum: one pk_add chain for {g,h}
static __device__ __forceinline__ f32x2 red16_sum2(f32x2 v) {
    f32x2 o;
    o[0] = dppmov<0x128>(v[0]); o[1] = dppmov<0x128>(v[1]); v = v + o;
    o[0] = dppmov<0x124>(v[0]); o[1] = dppmov<0x124>(v[1]); v = v + o;
    o[0] = dppmov<0x122>(v[0]); o[1] = dppmov<0x122>(v[1]); v = v + o;
    o[0] = dppmov<0x121>(v[0]); o[1] = dppmov<0x121>(v[1]); v = v + o;
    return v;
}

// ---------- fused prepass: K convert (blocks 0..2047), V transpose (2048..3071) ----------
__global__ __launch_bounds__(256) void prep_kv(
    const float* __restrict__ K, const float* __restrict__ V,
    unsigned short* __restrict__ Kbf, unsigned short* __restrict__ Vt)
{
    __shared__ float t[D_DIM * 65];
    const int tid = threadIdx.x;
    if (blockIdx.x < 2048) {
        const int idx = (blockIdx.x * 256 + tid) * 8;
        float4 a = *(const float4*)(K + idx);
        float4 b = *(const float4*)(K + idx + 4);
        uint4 o;
        o.x = bfpack(a.x, a.y); o.y = bfpack(a.z, a.w);
        o.z = bfpack(b.x, b.y); o.w = bfpack(b.z, b.w);
        *(uint4*)(Kbf + idx) = o;
    } else {
        const int blk = blockIdx.x - 2048;
        const int bh = blk >> 4;
        const int s0 = (blk & 15) * 64;
        const float* Vb = V + ((size_t)bh * S_LEN + s0) * D_DIM;
        const int sr = tid >> 4, d4 = (tid & 15) * 4;
        #pragma unroll
        for (int ii = 0; ii < 4; ++ii) {
            const int s = sr + 16 * ii;
            float4 v = *(const float4*)(Vb + s * D_DIM + d4);
            t[(d4+0)*65 + s] = v.x; t[(d4+1)*65 + s] = v.y;
            t[(d4+2)*65 + s] = v.z; t[(d4+3)*65 + s] = v.w;
        }
        __syncthreads();
        const int d = tid >> 2, sq = tid & 3;
        const float* tr = &t[d*65 + sq*16];
        uint4 o0, o1;
        o0.x = bfpack(tr[0],  tr[1]);  o0.y = bfpack(tr[2],  tr[3]);
        o0.z = bfpack(tr[4],  tr[5]);  o0.w = bfpack(tr[6],  tr[7]);
        o1.x = bfpack(tr[8],  tr[9]);  o1.y = bfpack(tr[10], tr[11]);
        o1.z = bfpack(tr[12], tr[13]); o1.w = bfpack(tr[14], tr[15]);
        unsigned short* outp = Vt + ((size_t)bh * D_DIM + d) * S_LEN + s0 + sq * 16;
        *(uint4*)(outp)     = o0;
        *(uint4*)(outp + 8) = o1;
    }
}

// ---------- main ----------
__global__ __launch_bounds__(256, 4) void entmax_attn_mfma(
    const float* __restrict__ Q, const unsigned short* __restrict__ Kbf,
    const unsigned short* __restrict__ Vt, float* __restrict__ O)
{
#pragma clang fp contract(fast)
    __shared__ __align__(16) unsigned short sQ[TQ * QPAD];      //  2304 B
    __shared__ __align__(16) unsigned short sP[TQ * PPAD];      // 33024 B
    __shared__ float sInv[TQ];                                  // ~35.4 KB total -> 4 blocks/CU

    const int tid  = threadIdx.x;
    const int lane = tid & 63;
    const int wave = tid >> 6;
    const int quad = lane >> 4;
    const int l15  = lane & 15;

    // XCD swizzle: pin each bh's 64 blocks to one XCD (blockIdx%8 = XCD).
    const int xcd = blockIdx.x & 7;
    const int kk  = blockIdx.x >> 3;
    const int bh  = (xcd << 3) | (kk >> 6);
    const int qt  = kk & 63;

    const float* Qb = Q + ((size_t)bh * S_LEN + qt * TQ) * D_DIM;
    const unsigned short* Kb = Kbf + (size_t)bh * S_LEN * D_DIM;
    const unsigned short* Vb = Vt  + (size_t)bh * D_DIM * S_LEN;

    // ---- stage Q tile (16x64 fp32 -> bf16, scale 1/16 folded in — exact) ----
    {
        const int r8 = tid >> 4, d04 = (tid & 15) * 4;
        float4 qv = *(const float4*)(Qb + r8 * D_DIM + d04);
        *(uint2*)(&sQ[r8 * QPAD + d04]) = make_uint2(
            bfpack(qv.x * 0.0625f, qv.y * 0.0625f),
            bfpack(qv.z * 0.0625f, qv.w * 0.0625f));
    }
    __syncthreads();                       // sQ visible

    // hoisted A-fragments (constant across K-loop)
    short8 a0 = *(const short8*)(&sQ[l15 * QPAD + quad * 8]);
    short8 a1 = *(const short8*)(&sQ[l15 * QPAD + 32 + quad * 8]);

    // ======= GEMM1: scores = (Q/16).K^T — direct global (L2), 2-tile-ahead =======
    // lane's B-fragments for tile kt: K[kt*64 + wave*16 + l15][quad*8 ..], +32.
    // Explicit rotation: c = tile kt, d = tile kt+1; issue kt+2 at iter kt.
    const int krow = wave * 16 + l15;
    const unsigned short* kfrag = Kb + (size_t)krow * D_DIM + quad * 8;
    short8 c0 = *(const short8*)(kfrag);
    short8 c1 = *(const short8*)(kfrag + 32);
    short8 d0 = *(const short8*)(kfrag + TK * D_DIM);
    short8 d1 = *(const short8*)(kfrag + TK * D_DIM + 32);
    #pragma unroll 2
    for (int kt = 0; kt < NT; ++kt) {
        const int ktp = (kt + 2 < NT) ? (kt + 2) : (NT - 1);   // clamped (redundant tail loads)
        const unsigned short* kp = kfrag + ktp * (TK * D_DIM);
        short8 e0 = *(const short8*)(kp);
        short8 e1 = *(const short8*)(kp + 32);
        f32x4 acc = {0.f, 0.f, 0.f, 0.f};
        acc = __builtin_amdgcn_mfma_f32_16x16x32_bf16(a0, c0, acc, 0, 0, 0);
        acc = __builtin_amdgcn_mfma_f32_16x16x32_bf16(a1, c1, acc, 0, 0, 0);
        const int col = kt * TK + krow;
        #pragma unroll
        for (int i = 0; i < 4; ++i)        // C: col=l15-derived, row=quad*4+i
            sP[(quad * 4 + i) * PPAD + col] = f2bf(acc[i]);
        c0 = d0; c1 = d1; d0 = e0; d1 = e1;
    }
    __syncthreads();                       // sP scores visible

    // ========== entmax-1.5: row = wave*4+quad, packed-f32, reg-pinned ==========
    {
        const int myrow = wave * 4 + quad;
        unsigned short* prow = &sP[myrow * PPAD];
        f32x2 xp[32];
        #pragma unroll
        for (int i = 0; i < 8; ++i) {
            uint4 c4 = *(const uint4*)(prow + (i * 16 + l15) * 8);
            xp[i*4+0] = (f32x2){bf_lo(c4.x), bf_hi(c4.x)};
            xp[i*4+1] = (f32x2){bf_lo(c4.y), bf_hi(c4.y)};
            xp[i*4+2] = (f32x2){bf_lo(c4.z), bf_hi(c4.z)};
            xp[i*4+3] = (f32x2){bf_lo(c4.w), bf_hi(c4.w)};
        }
        // pin the score array to VGPRs (defeat rematerialization)
        #pragma unroll
        for (int j = 0; j < 32; ++j) {
            double d = __builtin_bit_cast(double, xp[j]);
            asm volatile("" : "+v"(d));
            xp[j] = __builtin_bit_cast(f32x2, d);
        }

        // 4-way max tree (8-deep chains instead of 32)
        f32x2 ma = xp[0], mb = xp[1], mc = xp[2], md = xp[3];
        #pragma unroll
        for (int j = 4; j < 32; j += 4) {
            ma = __builtin_elementwise_max(ma, xp[j+0]);
            mb = __builtin_elementwise_max(mb, xp[j+1]);
            mc = __builtin_elementwise_max(mc, xp[j+2]);
            md = __builtin_elementwise_max(md, xp[j+3]);
        }
        ma = __builtin_elementwise_max(ma, mb);
        mc = __builtin_elementwise_max(mc, md);
        ma = __builtin_elementwise_max(ma, mc);
        float m = red16_max(fmaxf(ma[0], ma[1]));

        // Newton from below on convex decreasing g(tau)=sum (x-tau)+^2;
        // raw coordinates: root in [m-1, m), g(m-1) >= 1, monotone from below.
        // 5 iterations: quadratic convergence from width-1 bracket; final
        // renormalization by actual sum(p) absorbs residual tau error.
        const f32x2 z2 = {0.f, 0.f};
        float tau = m - 1.0f;
        #pragma unroll 1
        for (int it = 0; it < 5; ++it) {
            f32x2 ga = z2, gb = z2, gc = z2, gd = z2;
            f32x2 ha = z2, hb = z2, hc = z2, hd = z2;
            const f32x2 t2 = {tau, tau};
            #pragma unroll
            for (int j = 0; j < 32; j += 4) {
                f32x2 t0 = __builtin_elementwise_max(xp[j+0] - t2, z2);
                f32x2 t1 = __builtin_elementwise_max(xp[j+1] - t2, z2);
                f32x2 tt2 = __builtin_elementwise_max(xp[j+2] - t2, z2);
                f32x2 t3 = __builtin_elementwise_max(xp[j+3] - t2, z2);
                ga = t0 * t0 + ga;  ha = ha + t0;       // contracts to v_pk_fma_f32
                gb = t1 * t1 + gb;  hb = hb + t1;
                gc = tt2 * tt2 + gc; hc = hc + tt2;
                gd = t3 * t3 + gd;  hd = hd + t3;
            }
            f32x2 g2 = (ga + gb) + (gc + gd);
            f32x2 h2 = (ha + hb) + (hc + hd);
            f32x2 gh = red16_sum2((f32x2){g2[0] + g2[1], h2[0] + h2[1]});
            tau += (gh[0] - 1.0f) * __builtin_amdgcn_rcpf(gh[1] + gh[1]);
        }

        // p = (x - tau)+^2 -> bf16 (perm pair-pack), b128 stores; ps via
        // packed FMA on unrounded t^2 (renorm keeps output consistent)
        f32x2 ps2 = z2;
        const f32x2 tv = {tau, tau};
        #pragma unroll
        for (int i = 0; i < 8; ++i) {
            unsigned pk[4];
            #pragma unroll
            for (int w = 0; w < 4; ++w) {
                f32x2 t = __builtin_elementwise_max(xp[i*4+w] - tv, z2);
                f32x2 p = t * t;
                ps2 = t * t + ps2;             // v_pk_fma_f32
                pk[w] = bfpack(p[0], p[1]);
            }
            uint4 o; o.x = pk[0]; o.y = pk[1]; o.z = pk[2]; o.w = pk[3];
            *(uint4*)(prow + (i * 16 + l15) * 8) = o;
        }
        float ps = red16_sum(ps2[0] + ps2[1]);
        if (l15 == 0) sInv[myrow] = 1.0f / ps;
    }
    __syncthreads();                       // p-values + sInv visible

    // ======= GEMM2: O = P . V — direct global (L2), 2-tile-ahead =======
    // lane's B-fragments for tile kt: V^T[wave*16 + l15][kt*64 + quad*8 ..], +32.
    // sP A-fragments prefetched 1 tile ahead (LDS latency < L2).
    f32x4 oa = {0.f, 0.f, 0.f, 0.f};
    f32x4 ob = {0.f, 0.f, 0.f, 0.f};
    const int n0 = wave * 16;
    const unsigned short* vfrag = Vb + (size_t)(n0 + l15) * S_LEN + quad * 8;
    short8 v0 = *(const short8*)(vfrag);
    short8 v1 = *(const short8*)(vfrag + 32);
    short8 w0 = *(const short8*)(vfrag + TK);
    short8 w1 = *(const short8*)(vfrag + TK + 32);
    short8 pa0 = *(const short8*)(&sP[l15 * PPAD + quad * 8]);
    short8 pa1 = *(const short8*)(&sP[l15 * PPAD + 32 + quad * 8]);
    #pragma unroll 2
    for (int kt = 0; kt < NT; ++kt) {
        const int ktp = (kt + 2 < NT) ? (kt + 2) : (NT - 1);   // clamped
        short8 u0 = *(const short8*)(vfrag + ktp * TK);
        short8 u1 = *(const short8*)(vfrag + ktp * TK + 32);
        oa = __builtin_amdgcn_mfma_f32_16x16x32_bf16(pa0, v0, oa, 0, 0, 0);
        ob = __builtin_amdgcn_mfma_f32_16x16x32_bf16(pa1, v1, ob, 0, 0, 0);
        const int ktn = (kt + 1 < NT) ? (kt + 1) : (NT - 1);
        pa0 = *(const short8*)(&sP[l15 * PPAD + ktn * TK + quad * 8]);
        pa1 = *(const short8*)(&sP[l15 * PPAD + ktn * TK + 32 + quad * 8]);
        v0 = w0; v1 = w1; w0 = u0; w1 = u1;
    }
    f32x4 oacc = oa + ob;

    // ---- epilogue: renormalize + store ----
    float* Ob = O + ((size_t)bh * S_LEN + qt * TQ) * D_DIM;
    #pragma unroll
    for (int i = 0; i < 4; ++i) {
        const int row = quad * 4 + i;
        Ob[row * D_DIM + n0 + l15] = oacc[i] * sInv[row];
    }
}

extern "C" void kernel_launch(void* const* d_in, const int* in_sizes, int n_in,
                              void* d_out, int out_size, void* d_ws, size_t ws_size,
                              hipStream_t stream) {
    const float* q = (const float*)d_in[0];
    const float* k = (const float*)d_in[1];
    const float* v = (const float*)d_in[2];
    float* o = (float*)d_out;

    unsigned short* kbf = (unsigned short*)d_ws;                    // 8 MB
    unsigned short* vt  = kbf + (size_t)64 * S_LEN * D_DIM;         // 8 MB

    // fused prepass: 2048 K-convert blocks + 1024 V-transpose blocks
    prep_kv<<<3072, 256, 0, stream>>>(k, v, kbf, vt);
    // main: 64 bh x 64 q-tiles, XCD-swizzled
    entmax_attn_mfma<<<4096, 256, 0, stream>>>(q, kbf, vt, o);
}

// Round 12
// 176.487 us; speedup vs baseline: 1.2043x; 1.2043x over previous
//
#include <hip/hip_runtime.h>

// entmax-1.5 attention: B=8,H=8,S=1024,D=64, fp32 in/out.
// Prepass (fused): K -> bf16 ws; V -> bf16 transposed [bh][d][s] ws.
// Main: 16 q-rows/block; double-buffered 64x64 K/V tiles DMA'd via
// global_load_lds. Each wave stages+reads ONLY its own quarter of the tile
// (rows [wave*16, wave*16+16)) => per-tile block barriers replaced by
// per-wave counted s_waitcnt vmcnt(2); counted lgkm fences (4/2) guard the
// parity buffer. Cross-wave phases (sQ / sP-scores / p+sInv) keep real
// __syncthreads(). Round-12 = round-11 scheduling with Newton RESTORED to 5:
//  - r11's Newton-4 failed finite (absmax 0.137): 4 iters is below the
//    convergence edge; tau error shifts the support set, renorm can't fix.
//    NEWTON=5 IS THE FLOOR — axis closed.
//  - kept: GEMM1 delayed score-store BEFORE wait_vm (covers DMA window);
//    GEMM2 pan A-frag prefetch between DMA issue and wait_vm; unroll 2.
// Direct-global-load axis DEAD (r7, r10: compiler coalesces the rotation,
// VGPR->52, serial L2 latency). DMA kept.
// bf16 packing: manual f2bf RNE + v_perm_b32 pair-pack (same rounding bits).
// v_cvt_pk_bf16_f32 inline asm NaN'd in rounds 1-3 bisection — BANNED.
// entmax: per-row Newton, reg-pinned scores, packed-f32 math, DPP row_ror
// reduces, 4-way accumulator trees. GEMM2 dual MFMA accumulator.
// setprio around MFMA pairs. XCD-swizzled grid.

#define S_LEN 1024
#define D_DIM 64
#define TQ    16
#define TK    64
#define NT    (S_LEN / TK)    // 16 tiles
#define QPAD  72              // sQ row stride (bf16 elems)
#define PPAD  1032            // sP row stride (bf16 elems; 1032 => row stride
                              // == 4 banks mod 32: load-bearing for GEMM2-A reads)

typedef short  short8   __attribute__((ext_vector_type(8)));
typedef float  f32x4    __attribute__((ext_vector_type(4)));
typedef float  f32x2    __attribute__((ext_vector_type(2)));

static __device__ __forceinline__ unsigned short f2bf(float f) {
    unsigned u = __builtin_bit_cast(unsigned, f);
    u += 0x7FFFu + ((u >> 16) & 1u);           // RNE
    return (unsigned short)(u >> 16);
}
// RNE-round two f32 and pack their bf16s into one u32 via v_perm_b32.
// Bit-identical to f2bf(lo) | (f2bf(hi)<<16), fewer instructions.
static __device__ __forceinline__ unsigned bfpack(float lo, float hi) {
    unsigned ulo = __builtin_bit_cast(unsigned, lo);
    unsigned uhi = __builtin_bit_cast(unsigned, hi);
    ulo += 0x7FFFu + ((ulo >> 16) & 1u);
    uhi += 0x7FFFu + ((uhi >> 16) & 1u);
    return __builtin_amdgcn_perm(uhi, ulo, 0x07060302u);  // {uhi[31:16], ulo[31:16]}
}
static __device__ __forceinline__ float bf_lo(unsigned u) {
    return __builtin_bit_cast(float, u << 16);
}
static __device__ __forceinline__ float bf_hi(unsigned u) {
    return __builtin_bit_cast(float, u & 0xFFFF0000u);
}
static __device__ __forceinline__ void async16(const unsigned short* g, unsigned short* l) {
    __builtin_amdgcn_global_load_lds(
        (const __attribute__((address_space(1))) unsigned int*)g,
        (__attribute__((address_space(3))) unsigned int*)l, 16, 0, 0);
}
template<int N>
static __device__ __forceinline__ void wait_vm() {
    asm volatile("s_waitcnt vmcnt(%0)" :: "n"(N) : "memory");
}
template<int N>
static __device__ __forceinline__ void fence_lgkm() {
    // counted: only the OLD parity-buffer reads must be retired (they already
    // are, via the compiler's pre-MFMA wait + in-order DS completion); newer
    // stores/prefetch reads may stay pending. Memory clobber stops loads/DMA
    // crossing; VALU/MFMA scheduling stays free.
    asm volatile("s_waitcnt lgkmcnt(%0)" :: "n"(N) : "memory");
}

// 16-lane reduces via DPP row_ror (row = 16 lanes on CDNA). Rotation set
// {8,4,2,1} reaches all 16 lanes; VALU-speed vs ds_swizzle's ~30cyc.
template<int C>
static __device__ __forceinline__ float dppmov(float v) {
    return __builtin_bit_cast(float,
        __builtin_amdgcn_update_dpp(0, __builtin_bit_cast(int, v), C, 0xF, 0xF, true));
}
static __device__ __forceinline__ float red16_sum(float v) {
    v += dppmov<0x128>(v);   // row_ror:8
    v += dppmov<0x124>(v);   // row_ror:4
    v += dppmov<0x122>(v);   // row_ror:2
    v += dppmov<0x121>(v);   // row_ror:1
    return v;
}
static __device__ __forceinline__ float red16_max(float v) {
    v = fmaxf(v, dppmov<0x128>(v));
    v = fmaxf(v, dppmov<0x124>(v));
    v = fmaxf(v, dppmov<0x122>(v));
    v = fmaxf(v, dppmov<0x121>(v));
    return v;
}
// packed 2-channel 16-lane sum: one pk_add chain for {g,h}
static __device__ __forceinline__ f32x2 red16_sum2(f32x2 v) {
    f32x2 o;
    o[0] = dppmov<0x128>(v[0]); o[1] = dppmov<0x128>(v[1]); v = v + o;
    o[0] = dppmov<0x124>(v[0]); o[1] = dppmov<0x124>(v[1]); v = v + o;
    o[0] = dppmov<0x122>(v[0]); o[1] = dppmov<0x122>(v[1]); v = v + o;
    o[0] = dppmov<0x121>(v[0]); o[1] = dppmov<0x121>(v[1]); v = v + o;
    return v;
}

// ---------- fused prepass: K convert (blocks 0..2047), V transpose (2048..3071) ----------
__global__ __launch_bounds__(256) void prep_kv(
    const float* __restrict__ K, const float* __restrict__ V,
    unsigned short* __restrict__ Kbf, unsigned short* __restrict__ Vt)
{
    __shared__ float t[D_DIM * 65];
    const int tid = threadIdx.x;
    if (blockIdx.x < 2048) {
        const int idx = (blockIdx.x * 256 + tid) * 8;
        float4 a = *(const float4*)(K + idx);
        float4 b = *(const float4*)(K + idx + 4);
        uint4 o;
        o.x = bfpack(a.x, a.y); o.y = bfpack(a.z, a.w);
        o.z = bfpack(b.x, b.y); o.w = bfpack(b.z, b.w);
        *(uint4*)(Kbf + idx) = o;
    } else {
        const int blk = blockIdx.x - 2048;
        const int bh = blk >> 4;
        const int s0 = (blk & 15) * 64;
        const float* Vb = V + ((size_t)bh * S_LEN + s0) * D_DIM;
        const int sr = tid >> 4, d4 = (tid & 15) * 4;
        #pragma unroll
        for (int ii = 0; ii < 4; ++ii) {
            const int s = sr + 16 * ii;
            float4 v = *(const float4*)(Vb + s * D_DIM + d4);
            t[(d4+0)*65 + s] = v.x; t[(d4+1)*65 + s] = v.y;
            t[(d4+2)*65 + s] = v.z; t[(d4+3)*65 + s] = v.w;
        }
        __syncthreads();
        const int d = tid >> 2, sq = tid & 3;
        const float* tr = &t[d*65 + sq*16];
        uint4 o0, o1;
        o0.x = bfpack(tr[0],  tr[1]);  o0.y = bfpack(tr[2],  tr[3]);
        o0.z = bfpack(tr[4],  tr[5]);  o0.w = bfpack(tr[6],  tr[7]);
        o1.x = bfpack(tr[8],  tr[9]);  o1.y = bfpack(tr[10], tr[11]);
        o1.z = bfpack(tr[12], tr[13]); o1.w = bfpack(tr[14], tr[15]);
        unsigned short* outp = Vt + ((size_t)bh * D_DIM + d) * S_LEN + s0 + sq * 16;
        *(uint4*)(outp)     = o0;
        *(uint4*)(outp + 8) = o1;
    }
}

// ---------- main ----------
__global__ __launch_bounds__(256, 3) void entmax_attn_mfma(
    const float* __restrict__ Q, const unsigned short* __restrict__ Kbf,
    const unsigned short* __restrict__ Vt, float* __restrict__ O)
{
#pragma clang fp contract(fast)
    __shared__ __align__(16) unsigned short sQ[TQ * QPAD];      //  2304 B
    __shared__ __align__(16) unsigned short sP[TQ * PPAD];      // 33024 B
    __shared__ __align__(16) unsigned short sT[2][TK * D_DIM];  // 16384 B (dbuf K/V^T)
    __shared__ float sInv[TQ];

    const int tid  = threadIdx.x;
    const int lane = tid & 63;
    const int wave = tid >> 6;
    const int quad = lane >> 4;
    const int l15  = lane & 15;
    const int x7   = l15 & 7;

    // XCD swizzle: pin each bh's 64 blocks to one XCD (blockIdx%8 = XCD).
    const int xcd = blockIdx.x & 7;
    const int kk  = blockIdx.x >> 3;
    const int bh  = (xcd << 3) | (kk >> 6);
    const int qt  = kk & 63;

    const float* Qb = Q + ((size_t)bh * S_LEN + qt * TQ) * D_DIM;
    const unsigned short* Kb = Kbf + (size_t)bh * S_LEN * D_DIM;
    const unsigned short* Vb = Vt  + (size_t)bh * D_DIM * S_LEN;

    // staging geometry for 64x64 tiles (2 async16/thread), XOR chunk swizzle
    const int rl = lane >> 3;             // 0..7
    const int sc = (lane & 7) ^ rl;       // physical-chunk source (p = c ^ (r&7))

    // prefetch K tile 0 (this wave's quarter)
    async16(Kb + (size_t)(wave*16 + rl    ) * D_DIM + sc * 8, &sT[0][wave * 1024]);
    async16(Kb + (size_t)(wave*16 + rl + 8) * D_DIM + sc * 8, &sT[0][wave * 1024 + 512]);

    // ---- stage Q tile (16x64 fp32 -> bf16, scale 1/16 folded in — exact) ----
    {
        const int r8 = tid >> 4, d04 = (tid & 15) * 4;
        float4 qv = *(const float4*)(Qb + r8 * D_DIM + d04);
        *(uint2*)(&sQ[r8 * QPAD + d04]) = make_uint2(
            bfpack(qv.x * 0.0625f, qv.y * 0.0625f),
            bfpack(qv.z * 0.0625f, qv.w * 0.0625f));
    }
    __syncthreads();                       // sQ visible; K0 drained (full barrier)

    // hoisted A-fragments (constant across K-loop)
    short8 a0 = *(const short8*)(&sQ[l15 * QPAD + quad * 8]);
    short8 a1 = *(const short8*)(&sQ[l15 * QPAD + 32 + quad * 8]);

    // ======= GEMM1: scores = (Q/16).K^T — per-wave pipeline, no block barriers =======
    // Each wave stages and reads only rows [wave*16, wave*16+16) of each tile.
    // Delayed store BEFORE wait_vm: tile kt-1's score writes (vmcnt-independent)
    // cover part of tile kt's DMA-return window.
    const int krow = wave * 16 + l15;      // this wave's score-col within tile
    f32x4 accPrev;
    int colPrev = 0;
    #pragma unroll 2
    for (int kt = 0; kt < NT; ++kt) {
        fence_lgkm<4>();                   // prior parity reads retired (<=4 stores pending)
        if (kt < NT - 1) {                 // prefetch K tile kt+1
            const unsigned short* Ksrc = Kb + (size_t)(kt + 1) * TK * D_DIM;
            unsigned short* dst = &sT[(kt + 1) & 1][wave * 1024];
            async16(Ksrc + (size_t)(wave*16 + rl    ) * D_DIM + sc * 8, dst);
            async16(Ksrc + (size_t)(wave*16 + rl + 8) * D_DIM + sc * 8, dst + 512);
        } else {                           // prefetch V^T tile 0 (drained at barrier)
            unsigned short* dst = &sT[0][wave * 1024];
            async16(Vb + (size_t)(wave*16 + rl    ) * S_LEN + sc * 8, dst);
            async16(Vb + (size_t)(wave*16 + rl + 8) * S_LEN + sc * 8, dst + 512);
        }
        if (kt > 0) {                      // delayed store (fills DMA window)
            #pragma unroll
            for (int i = 0; i < 4; ++i)
                sP[(quad * 4 + i) * PPAD + colPrev] = f2bf(accPrev[i]);
        }
        wait_vm<2>();                      // tile kt resident; 2 newest still flying
        const unsigned short* bt = sT[kt & 1];
        short8 b0 = *(const short8*)(bt + krow * D_DIM + ((quad)     ^ x7) * 8);
        short8 b1 = *(const short8*)(bt + krow * D_DIM + ((quad + 4) ^ x7) * 8);
        f32x4 acc = {0.f, 0.f, 0.f, 0.f};
        __builtin_amdgcn_s_setprio(1);
        acc = __builtin_amdgcn_mfma_f32_16x16x32_bf16(a0, b0, acc, 0, 0, 0);
        acc = __builtin_amdgcn_mfma_f32_16x16x32_bf16(a1, b1, acc, 0, 0, 0);
        __builtin_amdgcn_s_setprio(0);
        accPrev = acc;
        colPrev = kt * TK + krow;
    }
    #pragma unroll
    for (int i = 0; i < 4; ++i)            // tail store (tile 15)
        sP[(quad * 4 + i) * PPAD + colPrev] = f2bf(accPrev[i]);
    __syncthreads();                       // sP scores visible; V0 drained

    // ========== entmax-1.5: row = wave*4+quad, packed-f32, reg-pinned ==========
    {
        const int myrow = wave * 4 + quad;
        unsigned short* prow = &sP[myrow * PPAD];
        f32x2 xp[32];
        #pragma unroll
        for (int i = 0; i < 8; ++i) {
            uint4 c4 = *(const uint4*)(prow + (i * 16 + l15) * 8);
            xp[i*4+0] = (f32x2){bf_lo(c4.x), bf_hi(c4.x)};
            xp[i*4+1] = (f32x2){bf_lo(c4.y), bf_hi(c4.y)};
            xp[i*4+2] = (f32x2){bf_lo(c4.z), bf_hi(c4.z)};
            xp[i*4+3] = (f32x2){bf_lo(c4.w), bf_hi(c4.w)};
        }
        // pin the score array to VGPRs (defeat rematerialization; LDS caps
        // occupancy at 3 blocks/CU so ~140 VGPRs is free)
        #pragma unroll
        for (int j = 0; j < 32; ++j) {
            double d = __builtin_bit_cast(double, xp[j]);
            asm volatile("" : "+v"(d));
            xp[j] = __builtin_bit_cast(f32x2, d);
        }

        // 4-way max tree (8-deep chains instead of 32)
        f32x2 ma = xp[0], mb = xp[1], mc = xp[2], md = xp[3];
        #pragma unroll
        for (int j = 4; j < 32; j += 4) {
            ma = __builtin_elementwise_max(ma, xp[j+0]);
            mb = __builtin_elementwise_max(mb, xp[j+1]);
            mc = __builtin_elementwise_max(mc, xp[j+2]);
            md = __builtin_elementwise_max(md, xp[j+3]);
        }
        ma = __builtin_elementwise_max(ma, mb);
        mc = __builtin_elementwise_max(mc, md);
        ma = __builtin_elementwise_max(ma, mc);
        float m = red16_max(fmaxf(ma[0], ma[1]));

        // Newton from below on convex decreasing g(tau)=sum (x-tau)+^2;
        // raw coordinates: root in [m-1, m), g(m-1) >= 1, monotone from below.
        // 5 iterations — THE FLOOR (r11: 4 iters -> absmax 0.137, support
        // misclassification; renorm can't absorb tau error, only sum error).
        const f32x2 z2 = {0.f, 0.f};
        float tau = m - 1.0f;
        #pragma unroll 1
        for (int it = 0; it < 5; ++it) {
            f32x2 ga = z2, gb = z2, gc = z2, gd = z2;
            f32x2 ha = z2, hb = z2, hc = z2, hd = z2;
            const f32x2 t2 = {tau, tau};
            #pragma unroll
            for (int j = 0; j < 32; j += 4) {
                f32x2 t0 = __builtin_elementwise_max(xp[j+0] - t2, z2);
                f32x2 t1 = __builtin_elementwise_max(xp[j+1] - t2, z2);
                f32x2 tt2 = __builtin_elementwise_max(xp[j+2] - t2, z2);
                f32x2 t3 = __builtin_elementwise_max(xp[j+3] - t2, z2);
                ga = t0 * t0 + ga;  ha = ha + t0;       // contracts to v_pk_fma_f32
                gb = t1 * t1 + gb;  hb = hb + t1;
                gc = tt2 * tt2 + gc; hc = hc + tt2;
                gd = t3 * t3 + gd;  hd = hd + t3;
            }
            f32x2 g2 = (ga + gb) + (gc + gd);
            f32x2 h2 = (ha + hb) + (hc + hd);
            f32x2 gh = red16_sum2((f32x2){g2[0] + g2[1], h2[0] + h2[1]});
            tau += (gh[0] - 1.0f) * __builtin_amdgcn_rcpf(gh[1] + gh[1]);
        }

        // p = (x - tau)+^2 -> bf16 (perm pair-pack), b128 stores; ps via
        // packed FMA on unrounded t^2 (renorm keeps output consistent)
        f32x2 ps2 = z2;
        const f32x2 tv = {tau, tau};
        #pragma unroll
        for (int i = 0; i < 8; ++i) {
            unsigned pk[4];
            #pragma unroll
            for (int w = 0; w < 4; ++w) {
                f32x2 t = __builtin_elementwise_max(xp[i*4+w] - tv, z2);
                f32x2 p = t * t;
                ps2 = t * t + ps2;             // v_pk_fma_f32
                pk[w] = bfpack(p[0], p[1]);
            }
            uint4 o; o.x = pk[0]; o.y = pk[1]; o.z = pk[2]; o.w = pk[3];
            *(uint4*)(prow + (i * 16 + l15) * 8) = o;
        }
        float ps = red16_sum(ps2[0] + ps2[1]);
        if (l15 == 0) sInv[myrow] = 1.0f / ps;
    }
    __syncthreads();                       // p-values + sInv visible

    // ======= GEMM2: O = P . V — per-wave pipeline, no block barriers =======
    // dual accumulator (per ks) halves the dependent MFMA chain depth;
    // next-tile sP A-fragments prefetched BETWEEN DMA issue and wait_vm
    // (pan rotation regs; fence<2> admits the 2 pending pan reads).
    f32x4 oa = {0.f, 0.f, 0.f, 0.f};
    f32x4 ob = {0.f, 0.f, 0.f, 0.f};
    const int n0 = wave * 16;
    short8 pa0 = *(const short8*)(&sP[l15 * PPAD + quad * 8]);
    short8 pa1 = *(const short8*)(&sP[l15 * PPAD + 32 + quad * 8]);
    #pragma unroll 2
    for (int kt = 0; kt < NT; ++kt) {
        fence_lgkm<2>();                   // prior parity reads retired (pan reads pending)
        short8 pan0, pan1;
        if (kt < NT - 1) {                 // prefetch V^T tile kt+1
            const unsigned short* Vsrc = Vb + (kt + 1) * TK;
            unsigned short* dst = &sT[(kt + 1) & 1][wave * 1024];
            async16(Vsrc + (size_t)(wave*16 + rl    ) * S_LEN + sc * 8, dst);
            async16(Vsrc + (size_t)(wave*16 + rl + 8) * S_LEN + sc * 8, dst + 512);
            // next A-frags issued here: their LDS latency covers the DMA wait
            pan0 = *(const short8*)(&sP[l15 * PPAD + (kt + 1) * TK + quad * 8]);
            pan1 = *(const short8*)(&sP[l15 * PPAD + (kt + 1) * TK + 32 + quad * 8]);
            wait_vm<2>();                  // tile kt resident
        } else {
            pan0 = pa0; pan1 = pa1;        // dummy (no next tile)
            wait_vm<0>();                  // last tile: drain everything
        }
        const unsigned short* bt = sT[kt & 1];
        short8 pb0 = *(const short8*)(bt + (n0 + l15) * D_DIM + ((quad)     ^ x7) * 8);
        short8 pb1 = *(const short8*)(bt + (n0 + l15) * D_DIM + ((4 + quad) ^ x7) * 8);
        __builtin_amdgcn_s_setprio(1);
        oa = __builtin_amdgcn_mfma_f32_16x16x32_bf16(pa0, pb0, oa, 0, 0, 0);
        ob = __builtin_amdgcn_mfma_f32_16x16x32_bf16(pa1, pb1, ob, 0, 0, 0);
        __builtin_amdgcn_s_setprio(0);
        pa0 = pan0; pa1 = pan1;
    }
    f32x4 oacc = oa + ob;

    // ---- epilogue: renormalize + store ----
    float* Ob = O + ((size_t)bh * S_LEN + qt * TQ) * D_DIM;
    #pragma unroll
    for (int i = 0; i < 4; ++i) {
        const int row = quad * 4 + i;
        Ob[row * D_DIM + n0 + l15] = oacc[i] * sInv[row];
    }
}

extern "C" void kernel_launch(void* const* d_in, const int* in_sizes, int n_in,
                              void* d_out, int out_size, void* d_ws, size_t ws_size,
                              hipStream_t stream) {
    const float* q = (const float*)d_in[0];
    const float* k = (const float*)d_in[1];
    const float* v = (const float*)d_in[2];
    float* o = (float*)d_out;

    unsigned short* kbf = (unsigned short*)d_ws;                    // 8 MB
    unsigned short* vt  = kbf + (size_t)64 * S_LEN * D_DIM;         // 8 MB

    // fused prepass: 2048 K-convert blocks + 1024 V-transpose blocks
    prep_kv<<<3072, 256, 0, stream>>>(k, v, kbf, vt);
    // main: 64 bh x 64 q-tiles, XCD-swizzled
    entmax_attn_mfma<<<4096, 256, 0, stream>>>(q, kbf, vt, o);
}